// Round 1
// baseline (1740.774 us; speedup 1.0000x reference)
//
#include <hip/hip_runtime.h>

#define IN_CH 128
#define HID 64

// ---------------- degree ----------------
__global__ __launch_bounds__(256) void k_deg_init(float* __restrict__ deg, int N) {
  int i = blockIdx.x * 256 + threadIdx.x;
  if (i < N) deg[i] = 1.0f;  // self-loop
}

__global__ __launch_bounds__(256) void k_deg_count(const int* __restrict__ dst,
                                                   float* __restrict__ deg, int E) {
  int i = blockIdx.x * 256 + threadIdx.x;
  if (i < E) unsafeAtomicAdd(&deg[dst[i]], 1.0f);
}

__global__ __launch_bounds__(256) void k_deg_finish(float* __restrict__ deg, int N) {
  int i = blockIdx.x * 256 + threadIdx.x;
  if (i < N) deg[i] = 1.0f / sqrtf(deg[i]);  // deg >= 1 always
}

// ---------------- layer-1 GEMM: g1 = (x @ W1) * dinv ; acc1 = g1 ----------------
// block = 256 threads, 64 nodes per block. Per wave: 16 nodes.
// lane = ng*16+cg -> thread computes nodes {w*16 + j*4 + ng} x channels {cg*4..+3}.
__global__ __launch_bounds__(256) void k_gemm1(const float* __restrict__ x,
    const float* __restrict__ W1, const float* __restrict__ dinv,
    float* __restrict__ g1, float* __restrict__ acc1, int N) {
  __shared__ __align__(16) float Ws[IN_CH * HID];  // 32 KB, [k][ch]
  __shared__ __align__(16) float xs[64 * IN_CH];   // 32 KB, col XOR-swizzled by (row&3)
  const int tid = threadIdx.x;
  const int base = blockIdx.x * 64;
  for (int i = tid; i < IN_CH * HID; i += 256) Ws[i] = W1[i];
  for (int i = tid; i < 64 * IN_CH; i += 256) {
    int row = i >> 7, col = i & 127;
    int n = base + row; if (n > N - 1) n = N - 1;
    xs[(row << 7) + (col ^ (row & 3))] = x[(size_t)n * IN_CH + col];
  }
  __syncthreads();
  const int w = tid >> 6, lane = tid & 63;
  const int ng = lane >> 4, cg = lane & 15;
  float acc[4][4];
  #pragma unroll
  for (int j = 0; j < 4; ++j)
    #pragma unroll
    for (int c = 0; c < 4; ++c) acc[j][c] = 0.f;
  #pragma unroll 8
  for (int k = 0; k < IN_CH; ++k) {
    float4 wv = *(const float4*)&Ws[(k << 6) + (cg << 2)];
    #pragma unroll
    for (int j = 0; j < 4; ++j) {
      int row = w * 16 + j * 4 + ng;              // row & 3 == ng
      float xv = xs[(row << 7) + (k ^ ng)];
      acc[j][0] = fmaf(xv, wv.x, acc[j][0]);
      acc[j][1] = fmaf(xv, wv.y, acc[j][1]);
      acc[j][2] = fmaf(xv, wv.z, acc[j][2]);
      acc[j][3] = fmaf(xv, wv.w, acc[j][3]);
    }
  }
  #pragma unroll
  for (int j = 0; j < 4; ++j) {
    int node = base + w * 16 + j * 4 + ng;
    if (node < N) {
      float di = dinv[node];
      float4 gv;
      gv.x = acc[j][0] * di; gv.y = acc[j][1] * di;
      gv.z = acc[j][2] * di; gv.w = acc[j][3] * di;
      *(float4*)&g1[(size_t)node * HID + (cg << 2)] = gv;
      *(float4*)&acc1[(size_t)node * HID + (cg << 2)] = gv;   // self-loop term
    }
  }
}

// ---------------- layer-2 GEMM: v = acc1*dinv + b1 ; g2 = (v @ W2)*dinv ; acc2 = g2 ----------------
__global__ __launch_bounds__(256) void k_gemm2(const float* __restrict__ accIn,
    const float* __restrict__ W2, const float* __restrict__ b1,
    const float* __restrict__ dinv,
    float* __restrict__ g2, float* __restrict__ acc2, int N) {
  __shared__ __align__(16) float Ws[HID * HID];  // 16 KB
  __shared__ __align__(16) float vs[64 * HID];   // 16 KB, swizzled
  const int tid = threadIdx.x;
  const int base = blockIdx.x * 64;
  for (int i = tid; i < HID * HID; i += 256) Ws[i] = W2[i];
  for (int i = tid; i < 64 * HID; i += 256) {
    int row = i >> 6, col = i & 63;
    int n = base + row; if (n > N - 1) n = N - 1;
    float v = fmaf(accIn[(size_t)n * HID + col], dinv[n], b1[col]);
    vs[(row << 6) + (col ^ (row & 3))] = v;
  }
  __syncthreads();
  const int w = tid >> 6, lane = tid & 63;
  const int ng = lane >> 4, cg = lane & 15;
  float acc[4][4];
  #pragma unroll
  for (int j = 0; j < 4; ++j)
    #pragma unroll
    for (int c = 0; c < 4; ++c) acc[j][c] = 0.f;
  #pragma unroll 8
  for (int k = 0; k < HID; ++k) {
    float4 wv = *(const float4*)&Ws[(k << 6) + (cg << 2)];
    #pragma unroll
    for (int j = 0; j < 4; ++j) {
      int row = w * 16 + j * 4 + ng;
      float xv = vs[(row << 6) + (k ^ ng)];
      acc[j][0] = fmaf(xv, wv.x, acc[j][0]);
      acc[j][1] = fmaf(xv, wv.y, acc[j][1]);
      acc[j][2] = fmaf(xv, wv.z, acc[j][2]);
      acc[j][3] = fmaf(xv, wv.w, acc[j][3]);
    }
  }
  #pragma unroll
  for (int j = 0; j < 4; ++j) {
    int node = base + w * 16 + j * 4 + ng;
    if (node < N) {
      float di = dinv[node];
      float4 gv;
      gv.x = acc[j][0] * di; gv.y = acc[j][1] * di;
      gv.z = acc[j][2] * di; gv.w = acc[j][3] * di;
      *(float4*)&g2[(size_t)node * HID + (cg << 2)] = gv;
      *(float4*)&acc2[(size_t)node * HID + (cg << 2)] = gv;
    }
  }
}

// ---------------- edge scatter: acc[dst] += g[src], one wave per edge ----------------
__global__ __launch_bounds__(256) void k_scatter(const int* __restrict__ src,
    const int* __restrict__ dst, const float* __restrict__ g,
    float* __restrict__ acc, int E) {
  const int lane = threadIdx.x & 63;
  int wid = (blockIdx.x * 256 + threadIdx.x) >> 6;
  wid = __builtin_amdgcn_readfirstlane(wid);
  const int nw = (gridDim.x * 256) >> 6;
  const int per = (E + nw - 1) / nw;
  int e0 = wid * per;
  int e1 = e0 + per; if (e1 > E) e1 = E;
  for (int e = e0; e < e1; ++e) {
    int s = src[e];
    int d = dst[e];
    unsafeAtomicAdd(&acc[(size_t)d * HID + lane], g[(size_t)s * HID + lane]);
  }
}

// ---------------- MLP head: out = relu(relu(v@lw1+lb1)@lw2+lb2)@lw3+lb3 ----------------
// v = acc2*dinv + b2. One wave per node, 4 nodes/wave sequential, 16 nodes/block.
__global__ __launch_bounds__(256) void k_mlp(const float* __restrict__ accIn,
    const float* __restrict__ dinv, const float* __restrict__ b2,
    const float* __restrict__ lw1, const float* __restrict__ lb1,
    const float* __restrict__ lw2, const float* __restrict__ lb2,
    const float* __restrict__ lw3, const float* __restrict__ lb3,
    float* __restrict__ out, int N) {
  __shared__ __align__(16) float w1s[64 * 64];  // 16 KB
  __shared__ __align__(16) float w2s[64 * 32];  // 8 KB
  __shared__ float w3s[32], b2s[64], lb1s[64], lb2s[32];
  __shared__ float vls[4][64], t1ls[4][64];
  const int tid = threadIdx.x;
  for (int i = tid; i < 4096; i += 256) w1s[i] = lw1[i];
  for (int i = tid; i < 2048; i += 256) w2s[i] = lw2[i];
  if (tid < 64) { b2s[tid] = b2[tid]; lb1s[tid] = lb1[tid]; }
  if (tid < 32) { w3s[tid] = lw3[tid]; lb2s[tid] = lb2[tid]; }
  const float lb3v = lb3[0];
  __syncthreads();
  const int w = tid >> 6, lane = tid & 63;
  const int base = blockIdx.x * 16;
  for (int rep = 0; rep < 4; ++rep) {
    int nd = base + w * 4 + rep;
    int node = nd < N ? nd : N - 1;
    float di = dinv[node];
    float v = fmaf(accIn[(size_t)node * HID + lane], di, b2s[lane]);
    vls[w][lane] = v;
    __syncthreads();
    float t1 = lb1s[lane];
    #pragma unroll
    for (int k = 0; k < 64; ++k) t1 = fmaf(vls[w][k], w1s[(k << 6) + lane], t1);
    t1 = fmaxf(t1, 0.f);
    t1ls[w][lane] = t1;
    __syncthreads();
    const int l2 = lane & 31;
    float t2 = lb2s[l2];
    #pragma unroll
    for (int k = 0; k < 64; ++k) t2 = fmaf(t1ls[w][k], w2s[(k << 5) + l2], t2);
    t2 = fmaxf(t2, 0.f);
    float p = (lane < 32) ? t2 * w3s[l2] : 0.f;
    #pragma unroll
    for (int m = 1; m < 64; m <<= 1) p += __shfl_xor(p, m, 64);
    if (lane == 0 && nd < N) out[nd] = p + lb3v;
    __syncthreads();
  }
}

extern "C" void kernel_launch(void* const* d_in, const int* in_sizes, int n_in,
                              void* d_out, int out_size, void* d_ws, size_t ws_size,
                              hipStream_t stream) {
  const float* x   = (const float*)d_in[0];
  const int*   ei  = (const int*)d_in[1];
  const float* W1  = (const float*)d_in[2];
  const float* b1  = (const float*)d_in[3];
  const float* W2  = (const float*)d_in[4];
  const float* b2  = (const float*)d_in[5];
  const float* lw1 = (const float*)d_in[6];
  const float* lb1 = (const float*)d_in[7];
  const float* lw2 = (const float*)d_in[8];
  const float* lb2 = (const float*)d_in[9];
  const float* lw3 = (const float*)d_in[10];
  const float* lb3 = (const float*)d_in[11];
  float* out = (float*)d_out;

  const int N = in_sizes[0] / IN_CH;
  const int E = in_sizes[1] / 2;
  const int* src = ei;
  const int* dst = ei + E;

  char* ws = (char*)d_ws;
  size_t degBytes = (((size_t)N * 4) + 255) & ~(size_t)255;
  float* deg  = (float*)ws;                       // N floats (becomes dinv)
  float* bufA = (float*)(ws + degBytes);          // N*64: g1, then g2
  float* bufB = bufA + (size_t)N * HID;           // N*64: acc1
  float* bufC = bufB + (size_t)N * HID;           // N*64: acc2

  const int nbN = (N + 255) / 256;
  const int nbE = (E + 255) / 256;
  const int gb  = (N + 63) / 64;

  hipLaunchKernelGGL(k_deg_init,   dim3(nbN),  dim3(256), 0, stream, deg, N);
  hipLaunchKernelGGL(k_deg_count,  dim3(nbE),  dim3(256), 0, stream, dst, deg, E);
  hipLaunchKernelGGL(k_deg_finish, dim3(nbN),  dim3(256), 0, stream, deg, N);

  hipLaunchKernelGGL(k_gemm1, dim3(gb), dim3(256), 0, stream, x, W1, deg, bufA, bufB, N);
  hipLaunchKernelGGL(k_scatter, dim3(2048), dim3(256), 0, stream, src, dst, bufA, bufB, E);
  hipLaunchKernelGGL(k_gemm2, dim3(gb), dim3(256), 0, stream, bufB, W2, b1, deg, bufA, bufC, N);
  hipLaunchKernelGGL(k_scatter, dim3(2048), dim3(256), 0, stream, src, dst, bufA, bufC, E);
  hipLaunchKernelGGL(k_mlp, dim3((N + 15) / 16), dim3(256), 0, stream,
                     bufC, deg, b2, lw1, lb1, lw2, lb2, lw3, lb3, out, N);
}

// Round 7
// 788.662 us; speedup vs baseline: 2.2072x; 2.2072x over previous
//
#include <hip/hip_runtime.h>

#define IN_CH 128
#define HID 64
#define SCAN_ELEMS 2048  // per block in scan kernels (256 thr x 8)

// ---------------- zero counters ----------------
__global__ __launch_bounds__(256) void k_zero(int* __restrict__ degInt,
                                              int* __restrict__ cursor, int N) {
  int i = blockIdx.x * 256 + threadIdx.x;
  if (i < N) { degInt[i] = 0; cursor[i] = 0; }
}

// ---------------- histogram of dst ----------------
__global__ __launch_bounds__(256) void k_hist(const int* __restrict__ dst,
                                              int* __restrict__ degInt, int E) {
  int i = blockIdx.x * 256 + threadIdx.x;
  if (i < E) atomicAdd(&degInt[dst[i]], 1);
}

// ---------------- scan pass 1: per-block exclusive scan + block sums ----------------
__global__ __launch_bounds__(256) void k_scan1(const int* __restrict__ degInt,
    int* __restrict__ rowptr, int* __restrict__ blockSums, int N) {
  __shared__ int lsum[256];
  const int tid = threadIdx.x;
  const int base = blockIdx.x * SCAN_ELEMS;
  int v[8]; int tsum = 0;
  #pragma unroll
  for (int i = 0; i < 8; ++i) {
    int gidx = base + tid * 8 + i;
    v[i] = (gidx < N) ? degInt[gidx] : 0;
    tsum += v[i];
  }
  lsum[tid] = tsum;
  __syncthreads();
  // Hillis-Steele inclusive scan over 256 thread sums
  #pragma unroll
  for (int off = 1; off < 256; off <<= 1) {
    int t = (tid >= off) ? lsum[tid - off] : 0;
    __syncthreads();
    lsum[tid] += t;
    __syncthreads();
  }
  int run = lsum[tid] - tsum;  // exclusive prefix of this thread's first element
  if (tid == 255) blockSums[blockIdx.x] = lsum[255];
  #pragma unroll
  for (int i = 0; i < 8; ++i) {
    int gidx = base + tid * 8 + i;
    if (gidx < N) rowptr[gidx] = run;
    run += v[i];
  }
}

// ---------------- scan pass 2: exclusive scan of block sums (1 wave) ----------------
__global__ __launch_bounds__(64) void k_scan2(int* __restrict__ bs, int nb) {
  const int lane = threadIdx.x;
  int offset = 0;
  for (int c = 0; c < nb; c += 64) {
    int v = (c + lane < nb) ? bs[c + lane] : 0;
    int orig = v;
    #pragma unroll
    for (int off = 1; off < 64; off <<= 1) {
      int t = __shfl_up(v, off, 64);
      if (lane >= off) v += t;
    }
    if (c + lane < nb) bs[c + lane] = offset + v - orig;
    offset += __shfl(v, 63, 64);
  }
}

// ---------------- scan pass 3: add block offsets; compute dinv ----------------
__global__ __launch_bounds__(256) void k_scan3(int* __restrict__ rowptr,
    const int* __restrict__ bs, const int* __restrict__ degInt,
    float* __restrict__ dinv, int N) {
  const int base = blockIdx.x * SCAN_ELEMS;
  const int add = bs[blockIdx.x];
  #pragma unroll
  for (int k = 0; k < 8; ++k) {
    int gidx = base + k * 256 + threadIdx.x;
    if (gidx < N) {
      rowptr[gidx] += add;
      dinv[gidx] = 1.0f / sqrtf((float)degInt[gidx] + 1.0f);  // +1 self-loop
    }
  }
}

// ---------------- bin edges into CSR ----------------
__global__ __launch_bounds__(256) void k_bin(const int* __restrict__ src,
    const int* __restrict__ dst, const int* __restrict__ rowptr,
    int* __restrict__ cursor, int* __restrict__ csr, int E) {
  int i = blockIdx.x * 256 + threadIdx.x;
  if (i < E) {
    int d = dst[i];
    int rp = rowptr[d];
    int p = atomicAdd(&cursor[d], 1);
    csr[rp + p] = src[i];
  }
}

// ---------------- layer-1 GEMM: g1 = (x @ W1) * dinv ----------------
// block = 256 threads, 64 nodes per block. Per wave: 16 nodes.
__global__ __launch_bounds__(256) void k_gemm1(const float* __restrict__ x,
    const float* __restrict__ W1, const float* __restrict__ dinv,
    float* __restrict__ g1, int N) {
  __shared__ __align__(16) float Ws[IN_CH * HID];  // 32 KB, [k][ch]
  __shared__ __align__(16) float xs[64 * IN_CH];   // 32 KB, col XOR-swizzled by (row&3)
  const int tid = threadIdx.x;
  const int base = blockIdx.x * 64;
  for (int i = tid; i < IN_CH * HID; i += 256) Ws[i] = W1[i];
  for (int i = tid; i < 64 * IN_CH; i += 256) {
    int row = i >> 7, col = i & 127;
    int n = base + row; if (n > N - 1) n = N - 1;
    xs[(row << 7) + (col ^ (row & 3))] = x[(size_t)n * IN_CH + col];
  }
  __syncthreads();
  const int w = tid >> 6, lane = tid & 63;
  const int ng = lane >> 4, cg = lane & 15;
  float acc[4][4];
  #pragma unroll
  for (int j = 0; j < 4; ++j)
    #pragma unroll
    for (int c = 0; c < 4; ++c) acc[j][c] = 0.f;
  #pragma unroll 8
  for (int k = 0; k < IN_CH; ++k) {
    float4 wv = *(const float4*)&Ws[(k << 6) + (cg << 2)];
    #pragma unroll
    for (int j = 0; j < 4; ++j) {
      int row = w * 16 + j * 4 + ng;              // row & 3 == ng
      float xv = xs[(row << 7) + (k ^ ng)];
      acc[j][0] = fmaf(xv, wv.x, acc[j][0]);
      acc[j][1] = fmaf(xv, wv.y, acc[j][1]);
      acc[j][2] = fmaf(xv, wv.z, acc[j][2]);
      acc[j][3] = fmaf(xv, wv.w, acc[j][3]);
    }
  }
  #pragma unroll
  for (int j = 0; j < 4; ++j) {
    int node = base + w * 16 + j * 4 + ng;
    if (node < N) {
      float di = dinv[node];
      float4 gv;
      gv.x = acc[j][0] * di; gv.y = acc[j][1] * di;
      gv.z = acc[j][2] * di; gv.w = acc[j][3] * di;
      *(float4*)&g1[(size_t)node * HID + (cg << 2)] = gv;
    }
  }
}

// ---------------- layer-2 GEMM: v = acc1*dinv + b1 ; g2 = (v @ W2)*dinv ----------------
__global__ __launch_bounds__(256) void k_gemm2(const float* __restrict__ accIn,
    const float* __restrict__ W2, const float* __restrict__ b1,
    const float* __restrict__ dinv,
    float* __restrict__ g2, int N) {
  __shared__ __align__(16) float Ws[HID * HID];  // 16 KB
  __shared__ __align__(16) float vs[64 * HID];   // 16 KB, swizzled
  const int tid = threadIdx.x;
  const int base = blockIdx.x * 64;
  for (int i = tid; i < HID * HID; i += 256) Ws[i] = W2[i];
  for (int i = tid; i < 64 * HID; i += 256) {
    int row = i >> 6, col = i & 63;
    int n = base + row; if (n > N - 1) n = N - 1;
    float v = fmaf(accIn[(size_t)n * HID + col], dinv[n], b1[col]);
    vs[(row << 6) + (col ^ (row & 3))] = v;
  }
  __syncthreads();
  const int w = tid >> 6, lane = tid & 63;
  const int ng = lane >> 4, cg = lane & 15;
  float acc[4][4];
  #pragma unroll
  for (int j = 0; j < 4; ++j)
    #pragma unroll
    for (int c = 0; c < 4; ++c) acc[j][c] = 0.f;
  #pragma unroll 8
  for (int k = 0; k < HID; ++k) {
    float4 wv = *(const float4*)&Ws[(k << 6) + (cg << 2)];
    #pragma unroll
    for (int j = 0; j < 4; ++j) {
      int row = w * 16 + j * 4 + ng;
      float xv = vs[(row << 6) + (k ^ ng)];
      acc[j][0] = fmaf(xv, wv.x, acc[j][0]);
      acc[j][1] = fmaf(xv, wv.y, acc[j][1]);
      acc[j][2] = fmaf(xv, wv.z, acc[j][2]);
      acc[j][3] = fmaf(xv, wv.w, acc[j][3]);
    }
  }
  #pragma unroll
  for (int j = 0; j < 4; ++j) {
    int node = base + w * 16 + j * 4 + ng;
    if (node < N) {
      float di = dinv[node];
      float4 gv;
      gv.x = acc[j][0] * di; gv.y = acc[j][1] * di;
      gv.z = acc[j][2] * di; gv.w = acc[j][3] * di;
      *(float4*)&g2[(size_t)node * HID + (cg << 2)] = gv;
    }
  }
}

// ---------------- gather: out[n] = g[n] + sum_{s in N(n)} g[s]  (no atomics) ----------------
// One wave per node; lane = channel. Indices broadcast via __shfl.
// 8-wide unroll: 8 independent 256B row loads in flight to cover L2/HBM latency.
__global__ __launch_bounds__(256) void k_gather(const int* __restrict__ rowptr,
    const int* __restrict__ degInt, const int* __restrict__ csr,
    const float* __restrict__ g, float* __restrict__ out, int N) {
  const int lane = threadIdx.x & 63;
  const int wid = (blockIdx.x * 256 + threadIdx.x) >> 6;  // node id
  if (wid >= N) return;
  const int start = rowptr[wid];
  const int deg = degInt[wid];
  float sum = g[(size_t)wid * HID + lane];  // self-loop term
  for (int c = 0; c < deg; c += 64) {
    int rem = deg - c;
    int cnt = rem < 64 ? rem : 64;
    int idx = 0;
    if (lane < cnt) idx = csr[start + c + lane];
    int j = 0;
    for (; j + 8 <= cnt; j += 8) {
      int s0 = __shfl(idx, j, 64);
      int s1 = __shfl(idx, j + 1, 64);
      int s2 = __shfl(idx, j + 2, 64);
      int s3 = __shfl(idx, j + 3, 64);
      int s4 = __shfl(idx, j + 4, 64);
      int s5 = __shfl(idx, j + 5, 64);
      int s6 = __shfl(idx, j + 6, 64);
      int s7 = __shfl(idx, j + 7, 64);
      float a0 = g[(size_t)s0 * HID + lane];
      float a1 = g[(size_t)s1 * HID + lane];
      float a2 = g[(size_t)s2 * HID + lane];
      float a3 = g[(size_t)s3 * HID + lane];
      float a4 = g[(size_t)s4 * HID + lane];
      float a5 = g[(size_t)s5 * HID + lane];
      float a6 = g[(size_t)s6 * HID + lane];
      float a7 = g[(size_t)s7 * HID + lane];
      sum += a0; sum += a1; sum += a2; sum += a3;
      sum += a4; sum += a5; sum += a6; sum += a7;
    }
    for (; j + 4 <= cnt; j += 4) {
      int s0 = __shfl(idx, j, 64);
      int s1 = __shfl(idx, j + 1, 64);
      int s2 = __shfl(idx, j + 2, 64);
      int s3 = __shfl(idx, j + 3, 64);
      float a0 = g[(size_t)s0 * HID + lane];
      float a1 = g[(size_t)s1 * HID + lane];
      float a2 = g[(size_t)s2 * HID + lane];
      float a3 = g[(size_t)s3 * HID + lane];
      sum += a0; sum += a1; sum += a2; sum += a3;
    }
    for (; j < cnt; ++j)
      sum += g[(size_t)__shfl(idx, j, 64) * HID + lane];
  }
  out[(size_t)wid * HID + lane] = sum;
}

// ---------------- MLP head ----------------
__global__ __launch_bounds__(256) void k_mlp(const float* __restrict__ accIn,
    const float* __restrict__ dinv, const float* __restrict__ b2,
    const float* __restrict__ lw1, const float* __restrict__ lb1,
    const float* __restrict__ lw2, const float* __restrict__ lb2,
    const float* __restrict__ lw3, const float* __restrict__ lb3,
    float* __restrict__ out, int N) {
  __shared__ __align__(16) float w1s[64 * 64];
  __shared__ __align__(16) float w2s[64 * 32];
  __shared__ float w3s[32], b2s[64], lb1s[64], lb2s[32];
  __shared__ float vls[4][64], t1ls[4][64];
  const int tid = threadIdx.x;
  for (int i = tid; i < 4096; i += 256) w1s[i] = lw1[i];
  for (int i = tid; i < 2048; i += 256) w2s[i] = lw2[i];
  if (tid < 64) { b2s[tid] = b2[tid]; lb1s[tid] = lb1[tid]; }
  if (tid < 32) { w3s[tid] = lw3[tid]; lb2s[tid] = lb2[tid]; }
  const float lb3v = lb3[0];
  __syncthreads();
  const int w = tid >> 6, lane = tid & 63;
  const int base = blockIdx.x * 16;
  for (int rep = 0; rep < 4; ++rep) {
    int nd = base + w * 4 + rep;
    int node = nd < N ? nd : N - 1;
    float di = dinv[node];
    float v = fmaf(accIn[(size_t)node * HID + lane], di, b2s[lane]);
    vls[w][lane] = v;
    __syncthreads();
    float t1 = lb1s[lane];
    #pragma unroll
    for (int k = 0; k < 64; ++k) t1 = fmaf(vls[w][k], w1s[(k << 6) + lane], t1);
    t1 = fmaxf(t1, 0.f);
    t1ls[w][lane] = t1;
    __syncthreads();
    const int l2 = lane & 31;
    float t2 = lb2s[l2];
    #pragma unroll
    for (int k = 0; k < 64; ++k) t2 = fmaf(t1ls[w][k], w2s[(k << 5) + l2], t2);
    t2 = fmaxf(t2, 0.f);
    float p = (lane < 32) ? t2 * w3s[l2] : 0.f;
    #pragma unroll
    for (int m = 1; m < 64; m <<= 1) p += __shfl_xor(p, m, 64);
    if (lane == 0 && nd < N) out[nd] = p + lb3v;
    __syncthreads();
  }
}

extern "C" void kernel_launch(void* const* d_in, const int* in_sizes, int n_in,
                              void* d_out, int out_size, void* d_ws, size_t ws_size,
                              hipStream_t stream) {
  const float* x   = (const float*)d_in[0];
  const int*   ei  = (const int*)d_in[1];
  const float* W1  = (const float*)d_in[2];
  const float* b1  = (const float*)d_in[3];
  const float* W2  = (const float*)d_in[4];
  const float* b2  = (const float*)d_in[5];
  const float* lw1 = (const float*)d_in[6];
  const float* lb1 = (const float*)d_in[7];
  const float* lw2 = (const float*)d_in[8];
  const float* lb2 = (const float*)d_in[9];
  const float* lw3 = (const float*)d_in[10];
  const float* lb3 = (const float*)d_in[11];
  float* out = (float*)d_out;

  const int N = in_sizes[0] / IN_CH;
  const int E = in_sizes[1] / 2;
  const int* src = ei;
  const int* dst = ei + E;

  auto align256 = [](size_t v) { return (v + 255) & ~(size_t)255; };
  char* ws = (char*)d_ws;
  size_t nB = align256((size_t)N * 4);
  float* dinv    = (float*)ws;                 ws += nB;
  int*   degInt  = (int*)ws;                   ws += nB;
  int*   rowptr  = (int*)ws;                   ws += nB;
  int*   cursor  = (int*)ws;                   ws += nB;
  int*   bsums   = (int*)ws;                   ws += align256(4096 * 4);
  int*   csr     = (int*)ws;                   ws += align256((size_t)E * 4);
  float* bufA    = (float*)ws;                 ws += (size_t)N * HID * 4;  // g1 / g2
  float* bufB    = (float*)ws;                 // acc1 / acc2

  const int nbN = (N + 255) / 256;
  const int nbE = (E + 255) / 256;
  const int nbScan = (N + SCAN_ELEMS - 1) / SCAN_ELEMS;
  const int gb  = (N + 63) / 64;
  const int gatherBlocks = (N * 64 + 255) / 256;

  // CSR build
  hipLaunchKernelGGL(k_zero,  dim3(nbN), dim3(256), 0, stream, degInt, cursor, N);
  hipLaunchKernelGGL(k_hist,  dim3(nbE), dim3(256), 0, stream, dst, degInt, E);
  hipLaunchKernelGGL(k_scan1, dim3(nbScan), dim3(256), 0, stream, degInt, rowptr, bsums, N);
  hipLaunchKernelGGL(k_scan2, dim3(1), dim3(64), 0, stream, bsums, nbScan);
  hipLaunchKernelGGL(k_scan3, dim3(nbScan), dim3(256), 0, stream, rowptr, bsums, degInt, dinv, N);
  hipLaunchKernelGGL(k_bin,   dim3(nbE), dim3(256), 0, stream, src, dst, rowptr, cursor, csr, E);

  // GCN layer 1
  hipLaunchKernelGGL(k_gemm1, dim3(gb), dim3(256), 0, stream, x, W1, dinv, bufA, N);
  hipLaunchKernelGGL(k_gather, dim3(gatherBlocks), dim3(256), 0, stream,
                     rowptr, degInt, csr, bufA, bufB, N);
  // GCN layer 2
  hipLaunchKernelGGL(k_gemm2, dim3(gb), dim3(256), 0, stream, bufB, W2, b1, dinv, bufA, N);
  hipLaunchKernelGGL(k_gather, dim3(gatherBlocks), dim3(256), 0, stream,
                     rowptr, degInt, csr, bufA, bufB, N);
  // MLP head
  hipLaunchKernelGGL(k_mlp, dim3((N + 15) / 16), dim3(256), 0, stream,
                     bufB, dinv, b2, lw1, lb1, lw2, lb2, lw3, lb3, out, N);
}